// Round 2
// baseline (3037.524 us; speedup 1.0000x reference)
//
#include <hip/hip_runtime.h>

typedef __bf16 bf16;
typedef __bf16 bf16x8 __attribute__((ext_vector_type(8)));
typedef float  f32x4  __attribute__((ext_vector_type(4)));

#define N_EMBD 1024
#define HEADS 16
#define DIM_HEAD 64

// ---------------------------------------------------------------- helpers

__device__ __forceinline__ void async_load16(const bf16* g, bf16* l) {
    __builtin_amdgcn_global_load_lds(
        (const __attribute__((address_space(1))) void*)g,
        (__attribute__((address_space(3))) void*)l, 16, 0, 0);
}

__device__ __forceinline__ float gelu_f(float x) {
    const float c = 0.7978845608028654f; // sqrt(2/pi)
    float u = c * (x + 0.044715f * x * x * x);
    return 0.5f * x * (1.0f + tanhf(u));
}

// ---------------------------------------------------------------- f32 -> bf16 convert

__global__ __launch_bounds__(256) void cvt_f32_bf16(const float* __restrict__ in,
                                                    bf16* __restrict__ out, int n) {
    int i = (blockIdx.x * 256 + threadIdx.x) * 8;
    if (i >= n) return;
    bf16x8 v;
    #pragma unroll
    for (int j = 0; j < 8; j++) v[j] = (bf16)in[i + j];
    *(bf16x8*)&out[i] = v;
}

// ---------------------------------------------------------------- transpose: f32 [R,C] -> bf16 [C,R]

__global__ __launch_bounds__(256) void transpose_k(const float* __restrict__ in,
                                                   bf16* __restrict__ out, int R, int C) {
    __shared__ bf16 tile[32][33];
    int c0 = blockIdx.x * 32, r0 = blockIdx.y * 32;
    int tx = threadIdx.x, ty = threadIdx.y; // (32,8)
    #pragma unroll
    for (int j = 0; j < 4; j++)
        tile[ty + j * 8][tx] = (bf16)in[(size_t)(r0 + ty + j * 8) * C + c0 + tx];
    __syncthreads();
    #pragma unroll
    for (int j = 0; j < 4; j++)
        out[(size_t)(c0 + ty + j * 8) * R + r0 + tx] = tile[tx][ty + j * 8];
}

// ---------------------------------------------------------------- LayerNorm: fp32 in -> bf16 out

__global__ __launch_bounds__(256) void ln_kernel(const float* __restrict__ x,
                                                 const float* __restrict__ w,
                                                 const float* __restrict__ b,
                                                 bf16* __restrict__ out) {
    int row = blockIdx.x;
    int tid = threadIdx.x;
    const float* xr = x + (size_t)row * N_EMBD;
    float4 v = *(const float4*)&xr[tid * 4];
    float s  = v.x + v.y + v.z + v.w;
    float s2 = v.x * v.x + v.y * v.y + v.z * v.z + v.w * v.w;
    #pragma unroll
    for (int off = 32; off >= 1; off >>= 1) {
        s  += __shfl_down(s, off);
        s2 += __shfl_down(s2, off);
    }
    __shared__ float red[8];
    int wave = tid >> 6, lane = tid & 63;
    if (lane == 0) { red[wave] = s; red[4 + wave] = s2; }
    __syncthreads();
    s  = red[0] + red[1] + red[2] + red[3];
    s2 = red[4] + red[5] + red[6] + red[7];
    float mu  = s * (1.0f / N_EMBD);
    float var = s2 * (1.0f / N_EMBD) - mu * mu;
    float r = 1.0f / sqrtf(var + 1e-5f);
    bf16* orow = out + (size_t)row * N_EMBD;
    float vv[4] = {v.x, v.y, v.z, v.w};
    #pragma unroll
    for (int j = 0; j < 4; j++) {
        int c = tid * 4 + j;
        float y = (vv[j] - mu) * r * w[c] + b[c];
        orow[c] = (bf16)y;
    }
}

// ---------------------------------------------------------------- GEMM: C[M,N] = A[M,K] * B[N,K]^T
// m97 structure: 128x128 tile, BK=64, 4 waves each 64x64, global_load_lds(16B) staging.
// Epilogue: optional bias (f32), optional GELU, output bf16 store or fp32 accumulate.

__global__ __launch_bounds__(256) void gemm_bt(
    const bf16* __restrict__ A, const bf16* __restrict__ B,
    bf16* __restrict__ Cout, float* __restrict__ Cacc,
    const float* __restrict__ bias,
    int M, int N, int K, int ldc, int act)
{
    __shared__ __align__(16) bf16 As[128][64];
    __shared__ __align__(16) bf16 Bs[128][64];
    const int tid  = threadIdx.x;
    const int wave = tid >> 6, lane = tid & 63;
    const int waveRow = (wave & 1) * 64, waveCol = (wave >> 1) * 64;
    const int blockN = blockIdx.x * 128, blockM = blockIdx.y * 128;

    f32x4 acc[4][4];
    #pragma unroll
    for (int r = 0; r < 4; r++)
        #pragma unroll
        for (int c = 0; c < 4; c++) acc[r][c] = (f32x4)0.0f;

    const int lr = lane >> 3;          // row-within-8 for staging
    const int lc = (lane & 7) * 8;     // k-chunk (elements)
    const size_t arow = (size_t)(blockM + wave * 32 + lr) * K;
    const size_t brow = (size_t)(blockN + wave * 32 + lr) * K;

    for (int k0 = 0; k0 < K; k0 += 64) {
        __syncthreads();
        #pragma unroll
        for (int i = 0; i < 4; i++) {
            async_load16(A + arow + (size_t)i * 8 * K + k0 + lc, &As[wave * 32 + i * 8][0]);
            async_load16(B + brow + (size_t)i * 8 * K + k0 + lc, &Bs[wave * 32 + i * 8][0]);
        }
        __syncthreads();
        #pragma unroll
        for (int ks = 0; ks < 2; ks++) {
            bf16x8 af[4], bq[4];
            #pragma unroll
            for (int r = 0; r < 4; r++)
                af[r] = *(const bf16x8*)&As[waveRow + r * 16 + (lane & 15)][ks * 32 + (lane >> 4) * 8];
            #pragma unroll
            for (int c = 0; c < 4; c++)
                bq[c] = *(const bf16x8*)&Bs[waveCol + c * 16 + (lane & 15)][ks * 32 + (lane >> 4) * 8];
            #pragma unroll
            for (int r = 0; r < 4; r++)
                #pragma unroll
                for (int c = 0; c < 4; c++)
                    acc[r][c] = __builtin_amdgcn_mfma_f32_16x16x32_bf16(af[r], bq[c], acc[r][c], 0, 0, 0);
        }
    }

    // epilogue: C/D layout col=lane&15, row=(lane>>4)*4+reg
    const int row0 = blockM + waveRow + ((lane >> 4) << 2);
    const int col0 = blockN + waveCol + (lane & 15);
    #pragma unroll
    for (int r = 0; r < 4; r++) {
        #pragma unroll
        for (int c = 0; c < 4; c++) {
            int cc = col0 + c * 16;
            float bv = bias ? bias[cc] : 0.0f;
            #pragma unroll
            for (int j = 0; j < 4; j++) {
                int row = row0 + r * 16 + j;
                float v = acc[r][c][j] + bv;
                if (act) v = gelu_f(v);
                if (Cacc) Cacc[(size_t)row * ldc + cc] += v;
                else      Cout[(size_t)row * ldc + cc] = (bf16)v;
            }
        }
    }
}

// ---------------------------------------------------------------- attention: one wave per (b,h)
// Online softmax; K/V staged through LDS in 64-row chunks; q and acc in registers.

__global__ __launch_bounds__(64) void attn_kernel(
    const bf16* __restrict__ Q, int ldq,
    const bf16* __restrict__ K, const bf16* __restrict__ V, int ldkv,
    bf16* __restrict__ O, int ldo,
    int T, int S, float scale)
{
    int b = blockIdx.x >> 4, h = blockIdx.x & 15;
    int t = threadIdx.x;
    __shared__ __align__(16) bf16 Ks[64][64];
    __shared__ __align__(16) bf16 Vs[64][64];

    const bf16* qrow = Q + (size_t)(b * T + (t < T ? t : 0)) * ldq + h * DIM_HEAD;
    float q[64];
    #pragma unroll
    for (int d0 = 0; d0 < 64; d0 += 8) {
        bf16x8 qq = *(const bf16x8*)&qrow[d0];
        #pragma unroll
        for (int j = 0; j < 8; j++) q[d0 + j] = (float)qq[j] * scale;
    }

    float m = -1e30f, l = 0.0f;
    float acc[64];
    #pragma unroll
    for (int d = 0; d < 64; d++) acc[d] = 0.0f;

    for (int s0 = 0; s0 < S; s0 += 64) {
        int ns = min(64, S - s0);
        __syncthreads();
        for (int i = threadIdx.x; i < ns * 8; i += 64) {
            int r = i >> 3, c = (i & 7) * 8;
            size_t g = (size_t)(b * S + s0 + r) * ldkv + h * DIM_HEAD + c;
            *(int4*)&Ks[r][c] = *(const int4*)&K[g];
            *(int4*)&Vs[r][c] = *(const int4*)&V[g];
        }
        __syncthreads();
        if (t < T) {
            for (int s = 0; s < ns; s++) {
                float dot = 0.0f;
                #pragma unroll
                for (int d0 = 0; d0 < 64; d0 += 8) {
                    bf16x8 kk = *(const bf16x8*)&Ks[s][d0];
                    #pragma unroll
                    for (int j = 0; j < 8; j++) dot += q[d0 + j] * (float)kk[j];
                }
                float mn = fmaxf(m, dot);
                float alpha = __expf(m - mn);
                float p = __expf(dot - mn);
                l = l * alpha + p;
                m = mn;
                #pragma unroll
                for (int d0 = 0; d0 < 64; d0 += 8) {
                    bf16x8 vv = *(const bf16x8*)&Vs[s][d0];
                    #pragma unroll
                    for (int j = 0; j < 8; j++)
                        acc[d0 + j] = acc[d0 + j] * alpha + p * (float)vv[j];
                }
            }
        }
    }
    if (t < T) {
        float inv = 1.0f / l;
        bf16* orow = O + (size_t)(b * T + t) * ldo + h * DIM_HEAD;
        #pragma unroll
        for (int d0 = 0; d0 < 64; d0 += 8) {
            bf16x8 ov;
            #pragma unroll
            for (int j = 0; j < 8; j++) ov[j] = (bf16)(acc[d0 + j] * inv);
            *(bf16x8*)&orow[d0] = ov;
        }
    }
}

// ---------------------------------------------------------------- launch

extern "C" void kernel_launch(void* const* d_in, const int* in_sizes, int n_in,
                              void* d_out, int out_size, void* d_ws, size_t ws_size,
                              hipStream_t stream) {
    const int B = 256, T = 60, S_IMG = 197, S_PR = 77;
    const int MQ = B * T;              // 15360
    const int M_PR = B * S_PR;         // 19712
    const float scale = 0.125f;        // 64^-0.5

    const float* x_in   = (const float*)d_in[0];
    const float* img    = (const float*)d_in[1];
    const float* prompt = (const float*)d_in[2];
    const float* ln1w = (const float*)d_in[3],  *ln1b = (const float*)d_in[4];
    const float* ln2w = (const float*)d_in[5],  *ln2b = (const float*)d_in[6];
    const float* ln3w = (const float*)d_in[7],  *ln3b = (const float*)d_in[8];
    const float* ln4w = (const float*)d_in[9],  *ln4b = (const float*)d_in[10];
    const float* sa_bo = (const float*)d_in[15];
    const float* ia_bo = (const float*)d_in[20];
    const float* pa_bo = (const float*)d_in[25];
    const float* fc_b  = (const float*)d_in[27];
    const float* pj_b  = (const float*)d_in[29];

    // workspace layout (bytes):
    //   x_f32 : 0          .. 62,914,560   (residual, fp32)
    //   h/ao  : 62,914,560 .. 94,371,840   (LN out & attn out, bf16, aliased)
    //   qkv   : 94,371,840 .. 188,743,680  (self QKV / cross Q, bf16)
    //   R     : 188,743,680.. 330,760,192  (img kv chunk + img_bf | prompt kv + prompt_bf | MLP hidden)
    //   wT    : 330,760,192.. 370,606,080  (transposed bf16 weights)
    char* ws = (char*)d_ws;
    float* x_f32 = (float*)ws;
    bf16*  h     = (bf16*)(ws + 62914560);
    bf16*  ao    = h;  // aliased: h dead before attention output is written
    bf16*  qkv   = (bf16*)(ws + 94371840);
    bf16*  Rkv   = (bf16*)(ws + 188743680);                 // kv / hidden
    bf16*  Rcv   = (bf16*)(ws + 188743680 + 103284736);     // img_bf / prompt_bf
    bf16*  wT    = (bf16*)(ws + 330760192);
    bf16*  hidden = Rkv;

    // --- transpose all weights f32 [K,N] -> bf16 [N,K] into wT
    struct TJ { int idx; size_t off; int R, C; };
    const TJ jobs[14] = {
        {11, 0,        1024, 1024},  // sa_wq  -> fused qkv [3072,1024]
        {12, 1048576,  1024, 1024},  // sa_wk
        {13, 2097152,  1024, 1024},  // sa_wv
        {14, 3145728,  1024, 1024},  // sa_wo
        {16, 4194304,  1024, 1024},  // ia_wq
        {17, 5242880,  768,  1024},  // ia_wk  -> fused kv [2048,768]
        {18, 6029312,  768,  1024},  // ia_wv
        {19, 6815744,  1024, 1024},  // ia_wo
        {21, 7864320,  1024, 1024},  // pa_wq
        {22, 8912896,  768,  1024},  // pa_wk
        {23, 9699328,  768,  1024},  // pa_wv
        {24, 10485760, 1024, 1024},  // pa_wo
        {26, 11534336, 1024, 4096},  // fc_w   -> [4096,1024]
        {28, 15728640, 4096, 1024},  // proj_w -> [1024,4096]
    };
    for (int i = 0; i < 14; i++) {
        dim3 g(jobs[i].C / 32, jobs[i].R / 32), blk(32, 8);
        transpose_k<<<g, blk, 0, stream>>>((const float*)d_in[jobs[i].idx], wT + jobs[i].off,
                                           jobs[i].R, jobs[i].C);
    }

    // residual init: x_f32 = x (f32 copy)
    hipMemcpyAsync(x_f32, x_in, (size_t)MQ * N_EMBD * 4, hipMemcpyDeviceToDevice, stream);

    auto gemm = [&](const bf16* A, const bf16* Bw, bf16* Co, float* Ca, const float* bias,
                    int M, int N, int K, int ldc, int act) {
        gemm_bt<<<dim3(N / 128, M / 128), 256, 0, stream>>>(A, Bw, Co, Ca, bias, M, N, K, ldc, act);
    };

    // ---- self attention
    ln_kernel<<<MQ, 256, 0, stream>>>(x_f32, ln1w, ln1b, h);
    gemm(h, wT + 0, qkv, nullptr, nullptr, MQ, 3072, 1024, 3072, 0);
    attn_kernel<<<B * HEADS, 64, 0, stream>>>(qkv, 3072, qkv + 1024, qkv + 2048, 3072,
                                              ao, 1024, T, T, scale);
    gemm(ao, wT + 3145728, nullptr, x_f32, sa_bo, MQ, 1024, 1024, 1024, 0);

    // ---- image cross attention (K/V chunked over 2 batch halves of 128)
    ln_kernel<<<MQ, 256, 0, stream>>>(x_f32, ln2w, ln2b, h);
    gemm(h, wT + 4194304, qkv, nullptr, nullptr, MQ, 1024, 1024, 1024, 0);
    {
        const int BC = 128, Mc = BC * S_IMG; // 25216
        for (int c = 0; c < 2; c++) {
            const float* imgc = img + (size_t)c * Mc * 768;
            cvt_f32_bf16<<<(Mc * 768) / 2048, 256, 0, stream>>>(imgc, Rcv, Mc * 768);
            gemm(Rcv, wT + 5242880, Rkv, nullptr, nullptr, Mc, 2048, 768, 2048, 0);
            attn_kernel<<<BC * HEADS, 64, 0, stream>>>(
                qkv + (size_t)c * BC * T * 1024, 1024, Rkv, Rkv + 1024, 2048,
                ao + (size_t)c * BC * T * 1024, 1024, T, S_IMG, scale);
        }
    }
    gemm(ao, wT + 6815744, nullptr, x_f32, ia_bo, MQ, 1024, 1024, 1024, 0);

    // ---- prompt cross attention
    ln_kernel<<<MQ, 256, 0, stream>>>(x_f32, ln3w, ln3b, h);
    gemm(h, wT + 7864320, qkv, nullptr, nullptr, MQ, 1024, 1024, 1024, 0);
    cvt_f32_bf16<<<(M_PR * 768) / 2048, 256, 0, stream>>>(prompt, Rcv, M_PR * 768);
    gemm(Rcv, wT + 8912896, Rkv, nullptr, nullptr, M_PR, 2048, 768, 2048, 0);
    attn_kernel<<<B * HEADS, 64, 0, stream>>>(qkv, 1024, Rkv, Rkv + 1024, 2048,
                                              ao, 1024, T, S_PR, scale);
    gemm(ao, wT + 10485760, nullptr, x_f32, pa_bo, MQ, 1024, 1024, 1024, 0);

    // ---- MLP
    ln_kernel<<<MQ, 256, 0, stream>>>(x_f32, ln4w, ln4b, h);
    gemm(h, wT + 11534336, hidden, nullptr, fc_b, MQ, 4096, 1024, 4096, 1);
    gemm(hidden, wT + 15728640, nullptr, x_f32, pj_b, MQ, 1024, 4096, 1024, 0);

    // output (f32)
    hipMemcpyAsync(d_out, x_f32, (size_t)MQ * N_EMBD * 4, hipMemcpyDeviceToDevice, stream);
}

// Round 3
// 2249.829 us; speedup vs baseline: 1.3501x; 1.3501x over previous
//
#include <hip/hip_runtime.h>

typedef __bf16 bf16;
typedef __bf16 bf16x8 __attribute__((ext_vector_type(8)));
typedef float  f32x4  __attribute__((ext_vector_type(4)));

#define N_EMBD 1024
#define HEADS 16
#define DIM_HEAD 64

// ---------------------------------------------------------------- helpers

__device__ __forceinline__ void async_load16(const bf16* g, bf16* l) {
    __builtin_amdgcn_global_load_lds(
        (const __attribute__((address_space(1))) void*)g,
        (__attribute__((address_space(3))) void*)l, 16, 0, 0);
}

__device__ __forceinline__ float gelu_f(float x) {
    const float c = 0.7978845608028654f; // sqrt(2/pi)
    float u = c * (x + 0.044715f * x * x * x);
    return 0.5f * x * (1.0f + tanhf(u));
}

// ---------------------------------------------------------------- f32 -> bf16 convert

__global__ __launch_bounds__(256) void cvt_f32_bf16(const float* __restrict__ in,
                                                    bf16* __restrict__ out, int n) {
    int i = (blockIdx.x * 256 + threadIdx.x) * 8;
    if (i >= n) return;
    bf16x8 v;
    #pragma unroll
    for (int j = 0; j < 8; j++) v[j] = (bf16)in[i + j];
    *(bf16x8*)&out[i] = v;
}

// ---------------------------------------------------------------- transpose: f32 [R,C] -> bf16 [C,R]

__global__ __launch_bounds__(256) void transpose_k(const float* __restrict__ in,
                                                   bf16* __restrict__ out, int R, int C) {
    __shared__ bf16 tile[32][33];
    int c0 = blockIdx.x * 32, r0 = blockIdx.y * 32;
    int tx = threadIdx.x, ty = threadIdx.y; // (32,8)
    #pragma unroll
    for (int j = 0; j < 4; j++)
        tile[ty + j * 8][tx] = (bf16)in[(size_t)(r0 + ty + j * 8) * C + c0 + tx];
    __syncthreads();
    #pragma unroll
    for (int j = 0; j < 4; j++)
        out[(size_t)(c0 + ty + j * 8) * R + r0 + tx] = tile[tx][ty + j * 8];
}

// ---------------------------------------------------------------- LayerNorm: fp32 in -> bf16 out

__global__ __launch_bounds__(256) void ln_kernel(const float* __restrict__ x,
                                                 const float* __restrict__ w,
                                                 const float* __restrict__ b,
                                                 bf16* __restrict__ out) {
    int row = blockIdx.x;
    int tid = threadIdx.x;
    const float* xr = x + (size_t)row * N_EMBD;
    float4 v = *(const float4*)&xr[tid * 4];
    float s  = v.x + v.y + v.z + v.w;
    float s2 = v.x * v.x + v.y * v.y + v.z * v.z + v.w * v.w;
    #pragma unroll
    for (int off = 32; off >= 1; off >>= 1) {
        s  += __shfl_down(s, off);
        s2 += __shfl_down(s2, off);
    }
    __shared__ float red[8];
    int wave = tid >> 6, lane = tid & 63;
    if (lane == 0) { red[wave] = s; red[4 + wave] = s2; }
    __syncthreads();
    s  = red[0] + red[1] + red[2] + red[3];
    s2 = red[4] + red[5] + red[6] + red[7];
    float mu  = s * (1.0f / N_EMBD);
    float var = s2 * (1.0f / N_EMBD) - mu * mu;
    float r = 1.0f / sqrtf(var + 1e-5f);
    bf16* orow = out + (size_t)row * N_EMBD;
    float vv[4] = {v.x, v.y, v.z, v.w};
    #pragma unroll
    for (int j = 0; j < 4; j++) {
        int c = tid * 4 + j;
        float y = (vv[j] - mu) * r * w[c] + b[c];
        orow[c] = (bf16)y;
    }
}

// ---------------------------------------------------------------- GEMM: C[M,N] = A[M,K] * B[N,K]^T

__global__ __launch_bounds__(256) void gemm_bt(
    const bf16* __restrict__ A, const bf16* __restrict__ B,
    bf16* __restrict__ Cout, float* __restrict__ Cacc,
    const float* __restrict__ bias,
    int M, int N, int K, int ldc, int act)
{
    __shared__ __align__(16) bf16 As[128][64];
    __shared__ __align__(16) bf16 Bs[128][64];
    const int tid  = threadIdx.x;
    const int wave = tid >> 6, lane = tid & 63;
    const int waveRow = (wave & 1) * 64, waveCol = (wave >> 1) * 64;
    const int blockN = blockIdx.x * 128, blockM = blockIdx.y * 128;

    f32x4 acc[4][4];
    #pragma unroll
    for (int r = 0; r < 4; r++)
        #pragma unroll
        for (int c = 0; c < 4; c++) acc[r][c] = (f32x4)0.0f;

    const int lr = lane >> 3;          // row-within-8 for staging
    const int lc = (lane & 7) * 8;     // k-chunk (elements)
    const size_t arow = (size_t)(blockM + wave * 32 + lr) * K;
    const size_t brow = (size_t)(blockN + wave * 32 + lr) * K;

    for (int k0 = 0; k0 < K; k0 += 64) {
        __syncthreads();
        #pragma unroll
        for (int i = 0; i < 4; i++) {
            async_load16(A + arow + (size_t)i * 8 * K + k0 + lc, &As[wave * 32 + i * 8][0]);
            async_load16(B + brow + (size_t)i * 8 * K + k0 + lc, &Bs[wave * 32 + i * 8][0]);
        }
        __syncthreads();
        #pragma unroll
        for (int ks = 0; ks < 2; ks++) {
            bf16x8 af[4], bq[4];
            #pragma unroll
            for (int r = 0; r < 4; r++)
                af[r] = *(const bf16x8*)&As[waveRow + r * 16 + (lane & 15)][ks * 32 + (lane >> 4) * 8];
            #pragma unroll
            for (int c = 0; c < 4; c++)
                bq[c] = *(const bf16x8*)&Bs[waveCol + c * 16 + (lane & 15)][ks * 32 + (lane >> 4) * 8];
            #pragma unroll
            for (int r = 0; r < 4; r++)
                #pragma unroll
                for (int c = 0; c < 4; c++)
                    acc[r][c] = __builtin_amdgcn_mfma_f32_16x16x32_bf16(af[r], bq[c], acc[r][c], 0, 0, 0);
        }
    }

    // epilogue: C/D layout col=lane&15, row=(lane>>4)*4+reg
    const int row0 = blockM + waveRow + ((lane >> 4) << 2);
    const int col0 = blockN + waveCol + (lane & 15);
    #pragma unroll
    for (int r = 0; r < 4; r++) {
        #pragma unroll
        for (int c = 0; c < 4; c++) {
            int cc = col0 + c * 16;
            float bv = bias ? bias[cc] : 0.0f;
            #pragma unroll
            for (int j = 0; j < 4; j++) {
                int row = row0 + r * 16 + j;
                float v = acc[r][c][j] + bv;
                if (act) v = gelu_f(v);
                if (Cacc) Cacc[(size_t)row * ldc + cc] += v;
                else      Cout[(size_t)row * ldc + cc] = (bf16)v;
            }
        }
    }
}

// ---------------------------------------------------------------- MFMA flash attention
// One block (4 waves) per (b,h). Wave w owns q-rows [w*16, w*16+16). T<=64.
// Per 64-key chunk: stage K[64x64] + V^T[64x72] in LDS, QK^T mfma, online
// softmax (shfl_xor row-reduce over 16 lanes), P -> LDS (C-layout->A-layout),
// PV mfma into f32 accumulators.

__global__ __launch_bounds__(256) void attn_mfma(
    const bf16* __restrict__ Q, int ldq,
    const bf16* __restrict__ K, const bf16* __restrict__ V, int ldkv,
    bf16* __restrict__ O, int ldo,
    int T, int S, float scale)
{
    const int b = blockIdx.x >> 4, h = blockIdx.x & 15;
    const int tid = threadIdx.x;
    const int wave = tid >> 6, lane = tid & 63;
    const int l15 = lane & 15, g = lane >> 4;

    __shared__ __align__(16) bf16 Ks[64][72];  // [s][d], padded pitch
    __shared__ __align__(16) bf16 Vt[64][72];  // [d][s], padded pitch
    __shared__ __align__(16) bf16 Ps[64][72];  // [q][s], padded pitch

    // Q fragment (A-layout): m = wave*16 + l15, k = g*8 + kk*32. Scale folded in.
    const int qm = wave * 16 + l15;
    const bf16* qrow = Q + (size_t)(b * T + (qm < T ? qm : 0)) * ldq + h * DIM_HEAD;
    bf16x8 aq[2];
    #pragma unroll
    for (int kk = 0; kk < 2; kk++) {
        bf16x8 t = *(const bf16x8*)&qrow[kk * 32 + g * 8];
        #pragma unroll
        for (int j = 0; j < 8; j++) t[j] = (bf16)((float)t[j] * scale);
        aq[kk] = t;
    }

    float m_run[4], l_run[4];
    f32x4 acc_o[4];
    #pragma unroll
    for (int r = 0; r < 4; r++) { m_run[r] = -1e30f; l_run[r] = 0.0f; acc_o[r] = (f32x4)0.0f; }

    for (int s0 = 0; s0 < S; s0 += 64) {
        __syncthreads();   // previous chunk's LDS reads done
        // stage K rows and V^T; 256 threads x 2 iters cover 64 rows x 64 cols
        for (int i = tid; i < 512; i += 256) {
            int r = i >> 3, c = (i & 7) * 8;
            int s = s0 + r;
            if (s < S) {
                size_t gidx = (size_t)(b * S + s) * ldkv + h * DIM_HEAD + c;
                *(int4*)&Ks[r][c] = *(const int4*)&K[gidx];
                bf16x8 v = *(const bf16x8*)&V[gidx];
                #pragma unroll
                for (int j = 0; j < 8; j++) Vt[c + j][r] = v[j];
            } else {
                int4 z; z.x = z.y = z.z = z.w = 0;
                *(int4*)&Ks[r][c] = z;
                #pragma unroll
                for (int j = 0; j < 8; j++) Vt[c + j][r] = (bf16)0.0f;
            }
        }
        __syncthreads();

        // QK^T: scores for 16 q-rows x 64 keys (4 n-tiles)
        f32x4 sc[4];
        #pragma unroll
        for (int jn = 0; jn < 4; jn++) {
            f32x4 s = (f32x4)0.0f;
            bf16x8 bk0 = *(const bf16x8*)&Ks[jn * 16 + l15][g * 8];
            bf16x8 bk1 = *(const bf16x8*)&Ks[jn * 16 + l15][32 + g * 8];
            s = __builtin_amdgcn_mfma_f32_16x16x32_bf16(aq[0], bk0, s, 0, 0, 0);
            s = __builtin_amdgcn_mfma_f32_16x16x32_bf16(aq[1], bk1, s, 0, 0, 0);
            sc[jn] = s;
        }
        // mask padded keys
        #pragma unroll
        for (int jn = 0; jn < 4; jn++)
            if (s0 + jn * 16 + l15 >= S) sc[jn] = (f32x4)(-1e30f);

        // online softmax; row = (g*4 + r), shared across the 16 lanes of l15
        float mx[4];
        #pragma unroll
        for (int r = 0; r < 4; r++)
            mx[r] = fmaxf(fmaxf(sc[0][r], sc[1][r]), fmaxf(sc[2][r], sc[3][r]));
        #pragma unroll
        for (int off = 1; off < 16; off <<= 1)
            #pragma unroll
            for (int r = 0; r < 4; r++) mx[r] = fmaxf(mx[r], __shfl_xor(mx[r], off));
        float al[4];
        #pragma unroll
        for (int r = 0; r < 4; r++) {
            float mn = fmaxf(m_run[r], mx[r]);
            al[r] = __expf(m_run[r] - mn);
            m_run[r] = mn;
        }
        float rs[4] = {0.f, 0.f, 0.f, 0.f};
        #pragma unroll
        for (int jn = 0; jn < 4; jn++)
            #pragma unroll
            for (int r = 0; r < 4; r++) {
                float p = __expf(sc[jn][r] - m_run[r]);
                sc[jn][r] = p;
                rs[r] += p;
            }
        #pragma unroll
        for (int off = 1; off < 16; off <<= 1)
            #pragma unroll
            for (int r = 0; r < 4; r++) rs[r] += __shfl_xor(rs[r], off);
        #pragma unroll
        for (int r = 0; r < 4; r++) l_run[r] = l_run[r] * al[r] + rs[r];
        #pragma unroll
        for (int jd = 0; jd < 4; jd++)
            #pragma unroll
            for (int r = 0; r < 4; r++) acc_o[jd][r] *= al[r];

        // P: C-layout -> LDS (each wave writes only its own 16 rows)
        #pragma unroll
        for (int jn = 0; jn < 4; jn++)
            #pragma unroll
            for (int r = 0; r < 4; r++)
                Ps[wave * 16 + g * 4 + r][jn * 16 + l15] = (bf16)sc[jn][r];
        __syncthreads();

        // PV: out += P[16x64] * V[64x64]  (B operand = V^T rows)
        #pragma unroll
        for (int kk = 0; kk < 2; kk++) {
            bf16x8 ap = *(const bf16x8*)&Ps[wave * 16 + l15][kk * 32 + g * 8];
            #pragma unroll
            for (int jd = 0; jd < 4; jd++) {
                bf16x8 bv = *(const bf16x8*)&Vt[jd * 16 + l15][kk * 32 + g * 8];
                acc_o[jd] = __builtin_amdgcn_mfma_f32_16x16x32_bf16(ap, bv, acc_o[jd], 0, 0, 0);
            }
        }
    }

    // epilogue: row q = wave*16 + g*4 + r, col d = jd*16 + l15
    #pragma unroll
    for (int r = 0; r < 4; r++) {
        int q = wave * 16 + g * 4 + r;
        if (q < T) {
            float inv = 1.0f / l_run[r];
            bf16* orow = O + (size_t)(b * T + q) * ldo + h * DIM_HEAD;
            #pragma unroll
            for (int jd = 0; jd < 4; jd++)
                orow[jd * 16 + l15] = (bf16)(acc_o[jd][r] * inv);
        }
    }
}

// ---------------------------------------------------------------- launch

extern "C" void kernel_launch(void* const* d_in, const int* in_sizes, int n_in,
                              void* d_out, int out_size, void* d_ws, size_t ws_size,
                              hipStream_t stream) {
    const int B = 256, T = 60, S_IMG = 197, S_PR = 77;
    const int MQ = B * T;              // 15360
    const int M_PR = B * S_PR;         // 19712
    const float scale = 0.125f;        // 64^-0.5

    const float* x_in   = (const float*)d_in[0];
    const float* img    = (const float*)d_in[1];
    const float* prompt = (const float*)d_in[2];
    const float* ln1w = (const float*)d_in[3],  *ln1b = (const float*)d_in[4];
    const float* ln2w = (const float*)d_in[5],  *ln2b = (const float*)d_in[6];
    const float* ln3w = (const float*)d_in[7],  *ln3b = (const float*)d_in[8];
    const float* ln4w = (const float*)d_in[9],  *ln4b = (const float*)d_in[10];
    const float* sa_bo = (const float*)d_in[15];
    const float* ia_bo = (const float*)d_in[20];
    const float* pa_bo = (const float*)d_in[25];
    const float* fc_b  = (const float*)d_in[27];
    const float* pj_b  = (const float*)d_in[29];

    // workspace layout (bytes):
    //   x_f32 : 0          .. 62,914,560   (residual, fp32)
    //   h/ao  : 62,914,560 .. 94,371,840   (LN out & attn out, bf16, aliased)
    //   qkv   : 94,371,840 .. 188,743,680  (self QKV / cross Q, bf16)
    //   R     : 188,743,680.. 330,760,192  (img kv chunk + img_bf | prompt kv + prompt_bf | MLP hidden)
    //   wT    : 330,760,192.. 370,606,080  (transposed bf16 weights)
    char* ws = (char*)d_ws;
    float* x_f32 = (float*)ws;
    bf16*  h     = (bf16*)(ws + 62914560);
    bf16*  ao    = h;  // aliased: h dead before attention output is written
    bf16*  qkv   = (bf16*)(ws + 94371840);
    bf16*  Rkv   = (bf16*)(ws + 188743680);                 // kv / hidden
    bf16*  Rcv   = (bf16*)(ws + 188743680 + 103284736);     // img_bf / prompt_bf
    bf16*  wT    = (bf16*)(ws + 330760192);
    bf16*  hidden = Rkv;

    // --- transpose all weights f32 [K,N] -> bf16 [N,K] into wT
    struct TJ { int idx; size_t off; int R, C; };
    const TJ jobs[14] = {
        {11, 0,        1024, 1024},  // sa_wq  -> fused qkv [3072,1024]
        {12, 1048576,  1024, 1024},  // sa_wk
        {13, 2097152,  1024, 1024},  // sa_wv
        {14, 3145728,  1024, 1024},  // sa_wo
        {16, 4194304,  1024, 1024},  // ia_wq
        {17, 5242880,  768,  1024},  // ia_wk  -> fused kv [2048,768]
        {18, 6029312,  768,  1024},  // ia_wv
        {19, 6815744,  1024, 1024},  // ia_wo
        {21, 7864320,  1024, 1024},  // pa_wq
        {22, 8912896,  768,  1024},  // pa_wk
        {23, 9699328,  768,  1024},  // pa_wv
        {24, 10485760, 1024, 1024},  // pa_wo
        {26, 11534336, 1024, 4096},  // fc_w   -> [4096,1024]
        {28, 15728640, 4096, 1024},  // proj_w -> [1024,4096]
    };
    for (int i = 0; i < 14; i++) {
        dim3 g(jobs[i].C / 32, jobs[i].R / 32), blk(32, 8);
        transpose_k<<<g, blk, 0, stream>>>((const float*)d_in[jobs[i].idx], wT + jobs[i].off,
                                           jobs[i].R, jobs[i].C);
    }

    // residual init: x_f32 = x (f32 copy)
    hipMemcpyAsync(x_f32, x_in, (size_t)MQ * N_EMBD * 4, hipMemcpyDeviceToDevice, stream);

    auto gemm = [&](const bf16* A, const bf16* Bw, bf16* Co, float* Ca, const float* bias,
                    int M, int N, int K, int ldc, int act) {
        gemm_bt<<<dim3(N / 128, M / 128), 256, 0, stream>>>(A, Bw, Co, Ca, bias, M, N, K, ldc, act);
    };

    // ---- self attention
    ln_kernel<<<MQ, 256, 0, stream>>>(x_f32, ln1w, ln1b, h);
    gemm(h, wT + 0, qkv, nullptr, nullptr, MQ, 3072, 1024, 3072, 0);
    attn_mfma<<<B * HEADS, 256, 0, stream>>>(qkv, 3072, qkv + 1024, qkv + 2048, 3072,
                                             ao, 1024, T, T, scale);
    gemm(ao, wT + 3145728, nullptr, x_f32, sa_bo, MQ, 1024, 1024, 1024, 0);

    // ---- image cross attention (K/V chunked over 2 batch halves of 128)
    ln_kernel<<<MQ, 256, 0, stream>>>(x_f32, ln2w, ln2b, h);
    gemm(h, wT + 4194304, qkv, nullptr, nullptr, MQ, 1024, 1024, 1024, 0);
    {
        const int BC = 128, Mc = BC * S_IMG; // 25216
        for (int c = 0; c < 2; c++) {
            const float* imgc = img + (size_t)c * Mc * 768;
            cvt_f32_bf16<<<(Mc * 768) / 2048, 256, 0, stream>>>(imgc, Rcv, Mc * 768);
            gemm(Rcv, wT + 5242880, Rkv, nullptr, nullptr, Mc, 2048, 768, 2048, 0);
            attn_mfma<<<BC * HEADS, 256, 0, stream>>>(
                qkv + (size_t)c * BC * T * 1024, 1024, Rkv, Rkv + 1024, 2048,
                ao + (size_t)c * BC * T * 1024, 1024, T, S_IMG, scale);
        }
    }
    gemm(ao, wT + 6815744, nullptr, x_f32, ia_bo, MQ, 1024, 1024, 1024, 0);

    // ---- prompt cross attention
    ln_kernel<<<MQ, 256, 0, stream>>>(x_f32, ln3w, ln3b, h);
    gemm(h, wT + 7864320, qkv, nullptr, nullptr, MQ, 1024, 1024, 1024, 0);
    cvt_f32_bf16<<<(M_PR * 768) / 2048, 256, 0, stream>>>(prompt, Rcv, M_PR * 768);
    gemm(Rcv, wT + 8912896, Rkv, nullptr, nullptr, M_PR, 2048, 768, 2048, 0);
    attn_mfma<<<B * HEADS, 256, 0, stream>>>(qkv, 1024, Rkv, Rkv + 1024, 2048,
                                             ao, 1024, T, S_PR, scale);
    gemm(ao, wT + 10485760, nullptr, x_f32, pa_bo, MQ, 1024, 1024, 1024, 0);

    // ---- MLP
    ln_kernel<<<MQ, 256, 0, stream>>>(x_f32, ln4w, ln4b, h);
    gemm(h, wT + 11534336, hidden, nullptr, fc_b, MQ, 4096, 1024, 4096, 1);
    gemm(hidden, wT + 15728640, nullptr, x_f32, pj_b, MQ, 1024, 4096, 1024, 0);

    // output (f32)
    hipMemcpyAsync(d_out, x_f32, (size_t)MQ * N_EMBD * 4, hipMemcpyDeviceToDevice, stream);
}